// Round 3
// baseline (1057.328 us; speedup 1.0000x reference)
//
#include <hip/hip_runtime.h>
#include <stdint.h>
#include <stddef.h>

#define M_SZ 8192
#define F_DIM 512
#define N_Q 32768

typedef __attribute__((ext_vector_type(4))) float f32x4;
typedef __attribute__((ext_vector_type(8))) __bf16 bf16x8;
typedef __attribute__((ext_vector_type(2))) __bf16 bf16x2;

__device__ __forceinline__ float bits_to_f(unsigned u) {
    union { unsigned u; float f; } v; v.u = u; return v.f;
}
// Pack two floats to bf16 pair (RNE, native cvt on gfx950). Low 16 = a.
__device__ __forceinline__ unsigned pk_bf16(float a, float b) {
    union { bf16x2 v; unsigned u; } cv;
    cv.v.x = (__bf16)a; cv.v.y = (__bf16)b;
    return cv.u;
}
__device__ __forceinline__ unsigned short f2bf(float x) {
    union { bf16x2 v; unsigned u; } cv;
    cv.v.x = (__bf16)x; cv.v.y = (__bf16)0.0f;
    return (unsigned short)(cv.u & 0xffffu);
}

// ---------------------------------------------------------------------------
// Kernel 1: row-normalize positions & embeddings; pad to float4 for staging.
// ---------------------------------------------------------------------------
__global__ void prep_kernel(const float* __restrict__ pos,
                            const float* __restrict__ emb,
                            float* __restrict__ pn4,
                            float* __restrict__ en4,
                            float* __restrict__ pos4) {
    int i = blockIdx.x * 256 + threadIdx.x;
    if (i >= M_SZ) return;
    float x = pos[i * 3 + 0], y = pos[i * 3 + 1], z = pos[i * 3 + 2];
    float inv = 1.0f / __builtin_amdgcn_sqrtf(x * x + y * y + z * z);
    pn4[i * 4 + 0] = x * inv; pn4[i * 4 + 1] = y * inv;
    pn4[i * 4 + 2] = z * inv; pn4[i * 4 + 3] = 0.0f;
    pos4[i * 4 + 0] = x; pos4[i * 4 + 1] = y;
    pos4[i * 4 + 2] = z; pos4[i * 4 + 3] = 0.0f;
    float ex = emb[i * 3 + 0], ey = emb[i * 3 + 1], ez = emb[i * 3 + 2];
    float einv = 1.0f / __builtin_amdgcn_sqrtf(ex * ex + ey * ey + ez * ez);
    en4[i * 4 + 0] = ex * einv; en4[i * 4 + 1] = ey * einv;
    en4[i * 4 + 2] = ez * einv; en4[i * 4 + 3] = 0.0f;
}

// ---------------------------------------------------------------------------
// Kernel 2: features [8192,512] fp32 -> featT [512,8192] bf16.
// ---------------------------------------------------------------------------
__global__ void transpose_kernel(const float* __restrict__ feat,
                                 unsigned short* __restrict__ featT) {
    __shared__ float tile[64 * 65];
    const int jb = blockIdx.x * 64, fb = blockIdx.y * 64;
    const int t = threadIdx.x;
#pragma unroll
    for (int p = 0; p < 16; ++p) {
        int idx = p * 256 + t;
        int j = idx >> 6, f = idx & 63;
        tile[j * 65 + f] = feat[(size_t)(jb + j) * F_DIM + fb + f];
    }
    __syncthreads();
#pragma unroll
    for (int p = 0; p < 16; ++p) {
        int idx = p * 256 + t;
        int f = idx >> 6, j = idx & 63;
        featT[(size_t)(fb + f) * M_SZ + jb + j] = f2bf(tile[j * 65 + f]);
    }
}

// ---------------------------------------------------------------------------
// Kernel 3: fused softmax(pn@en^T) @ [features | positions].
// BM=32 (m rows), BN=256 (f cols, 2 y-blocks), BK=32. Grid 512 -> 2 blocks/CU
// for cross-block VALU/MFMA overlap. en/pos read direct from L1 (uniform).
// ---------------------------------------------------------------------------
__launch_bounds__(256, 2)
__global__ void build_memory_kernel(const float* __restrict__ pn4,
                                    const float* __restrict__ en4,
                                    const float* __restrict__ pos4,
                                    const unsigned short* __restrict__ featT,
                                    unsigned short* __restrict__ memT,
                                    float* __restrict__ npe4) {
    constexpr int BM = 32, BN = 256, BK = 32;
    constexpr int PSTR = BK + 8;  // 40 bf16 = 80 B
    __shared__ unsigned short pbuf[BM * PSTR];
    __shared__ unsigned short vbuf[BN * PSTR];
    __shared__ f32x4 red[256];
    __shared__ float lbuf[BM];

    const int t = threadIdx.x;
    const int lane = t & 63, wv = t >> 6;
    const int mb = blockIdx.x * BM, fb = blockIdx.y * BN;
    const int r = t & 31, jq = t >> 5;  // P-row, j-group (4 j's each)

    const f32x4 pnr = ((const f32x4*)pn4)[mb + r];

    f32x4 acc[2][4];
    const f32x4 zero4 = {0.f, 0.f, 0.f, 0.f};
#pragma unroll
    for (int m = 0; m < 2; ++m)
#pragma unroll
        for (int n = 0; n < 4; ++n) acc[m][n] = zero4;
    float nx = 0.f, ny = 0.f, nz = 0.f, lp = 0.f;

    const unsigned short* vsrc = featT + (size_t)(fb + t) * M_SZ;
    const f32x4* en = (const f32x4*)en4;
    const f32x4* ps = (const f32x4*)pos4;

    for (int kt = 0; kt < M_SZ / BK; ++kt) {
        const int jb2 = kt * BK;
        const uint4* g = (const uint4*)(vsrc + jb2);
        uint4 v0 = g[0], v1 = g[1], v2 = g[2], v3 = g[3];

        unsigned pk2[2];
#pragma unroll
        for (int i = 0; i < 4; i += 2) {
            int j = jb2 + jq * 4 + i;
            f32x4 e0 = en[j], e1 = en[j + 1];
            f32x4 p0 = ps[j], p1 = ps[j + 1];
            float s0 = fmaf(pnr.x, e0.x, fmaf(pnr.y, e0.y, pnr.z * e0.z));
            float s1 = fmaf(pnr.x, e1.x, fmaf(pnr.y, e1.y, pnr.z * e1.z));
            float w0 = __builtin_amdgcn_exp2f(s0 * 1.44269504f);
            float w1 = __builtin_amdgcn_exp2f(s1 * 1.44269504f);
            unsigned u = pk_bf16(w0, w1);
            float w0r = bits_to_f(u << 16);
            float w1r = bits_to_f(u & 0xffff0000u);
            lp += w0r + w1r;
            nx = fmaf(w0r, p0.x, fmaf(w1r, p1.x, nx));
            ny = fmaf(w0r, p0.y, fmaf(w1r, p1.y, ny));
            nz = fmaf(w0r, p0.z, fmaf(w1r, p1.z, nz));
            pk2[i >> 1] = u;
        }
        __syncthreads();  // prev iter's fragment reads done
        *(uint2*)(pbuf + r * PSTR + jq * 4) = make_uint2(pk2[0], pk2[1]);
        uint4* vd = (uint4*)(vbuf + t * PSTR);
        vd[0] = v0; vd[1] = v1; vd[2] = v2; vd[3] = v3;
        __syncthreads();  // pbuf/vbuf visible

        const int col = lane & 15, quad = lane >> 4;
        bf16x8 a[2];
#pragma unroll
        for (int m = 0; m < 2; ++m)
            a[m] = *(const bf16x8*)(pbuf + (m * 16 + col) * PSTR + quad * 8);
#pragma unroll
        for (int n = 0; n < 4; ++n) {
            bf16x8 b = *(const bf16x8*)(vbuf + ((wv * 4 + n) * 16 + col) * PSTR + quad * 8);
#pragma unroll
            for (int m = 0; m < 2; ++m)
                acc[m][n] = __builtin_amdgcn_mfma_f32_16x16x32_bf16(a[m], b, acc[m][n], 0, 0, 0);
        }
    }

    f32x4 mine = {nx, ny, nz, lp};
    red[t] = mine;
    __syncthreads();
    if (t < BM) {
        f32x4 s = red[t];
#pragma unroll
        for (int gI = 1; gI < 8; ++gI) {
            f32x4 o = red[t + 32 * gI];
            s.x += o.x; s.y += o.y; s.z += o.z; s.w += o.w;
        }
        lbuf[t] = s.w;
        if (blockIdx.y == 0) {
            float inv = 1.0f / s.w;
            float X = s.x * inv, Y = s.y * inv, Z = s.z * inv;
            f32x4 o = {X, Y, Z, X * X + Y * Y + Z * Z};
            ((f32x4*)npe4)[mb + t] = o;
        }
    }
    __syncthreads();

    const int col = lane & 15, quad = lane >> 4;
#pragma unroll
    for (int m = 0; m < 2; ++m) {
        f32x4 l4 = *(const f32x4*)(lbuf + m * 16 + quad * 4);
        f32x4 inv4 = {1.0f / l4.x, 1.0f / l4.y, 1.0f / l4.z, 1.0f / l4.w};
        int mg = mb + m * 16 + quad * 4;
#pragma unroll
        for (int n = 0; n < 4; ++n) {
            int fg = fb + (wv * 4 + n) * 16 + col;
            ushort4 o;
            o.x = f2bf(acc[m][n].x * inv4.x);
            o.y = f2bf(acc[m][n].y * inv4.y);
            o.z = f2bf(acc[m][n].z * inv4.z);
            o.w = f2bf(acc[m][n].w * inv4.w);
            *(ushort4*)(memT + (size_t)fg * M_SZ + mg) = o;
        }
    }
}

// ---------------------------------------------------------------------------
// Kernel 4: fused softmax(-cdist(q, npe)) @ memory.
// BM=64 queries, BN=512 (ALL F cols -> P computed once), BK=32.
// Grid 512 -> 2 blocks/CU desync overlap. npe read direct (uniform, L1).
// ---------------------------------------------------------------------------
__launch_bounds__(256, 2)
__global__ void query_kernel(const float* __restrict__ qpos,
                             const float* __restrict__ npe4,
                             const unsigned short* __restrict__ memT,
                             float* __restrict__ out) {
    constexpr int BM = 64, BN = 512, BK = 32;
    constexpr int PSTR = BK + 8;  // 40
    __shared__ unsigned short pbuf[BM * PSTR];   // 5120 B
    __shared__ unsigned short vbuf[BN * PSTR];   // 40960 B
    __shared__ float red[256];
    __shared__ float lbuf[BM];

    const int t = threadIdx.x;
    const int lane = t & 63, wv = t >> 6;
    const int qb = blockIdx.x * BM;
    const int r = t & 63, jq = t >> 6;  // P-row, j-group (8 j's each)

    const float qx = qpos[(size_t)(qb + r) * 3 + 0];
    const float qy = qpos[(size_t)(qb + r) * 3 + 1];
    const float qz = qpos[(size_t)(qb + r) * 3 + 2];
    const float q2 = qx * qx + qy * qy + qz * qz;
    const float m2x = -2.0f * qx, m2y = -2.0f * qy, m2z = -2.0f * qz;

    f32x4 acc[4][8];
    const f32x4 zero4 = {0.f, 0.f, 0.f, 0.f};
#pragma unroll
    for (int m = 0; m < 4; ++m)
#pragma unroll
        for (int n = 0; n < 8; ++n) acc[m][n] = zero4;
    float lp = 0.f;

    const unsigned short* vsrc0 = memT + (size_t)t * M_SZ;
    const unsigned short* vsrc1 = memT + (size_t)(t + 256) * M_SZ;
    const f32x4* nsrc = (const f32x4*)npe4;

    for (int kt = 0; kt < M_SZ / BK; ++kt) {
        const int jb2 = kt * BK;
        const uint4* g0 = (const uint4*)(vsrc0 + jb2);
        const uint4* g1 = (const uint4*)(vsrc1 + jb2);
        uint4 va0 = g0[0], va1 = g0[1], va2 = g0[2], va3 = g0[3];
        uint4 vb0 = g1[0], vb1 = g1[1], vb2 = g1[2], vb3 = g1[3];

        unsigned pk4[4];
#pragma unroll
        for (int i = 0; i < 8; i += 2) {
            int j = jb2 + jq * 8 + i;
            f32x4 n0 = nsrc[j], n1 = nsrc[j + 1];
            float s0 = fmaf(m2x, n0.x, fmaf(m2y, n0.y, fmaf(m2z, n0.z, q2 + n0.w)));
            float s1 = fmaf(m2x, n1.x, fmaf(m2y, n1.y, fmaf(m2z, n1.z, q2 + n1.w)));
            s0 = fmaxf(s0, 1e-12f);
            s1 = fmaxf(s1, 1e-12f);
            float w0 = __builtin_amdgcn_exp2f(__builtin_amdgcn_sqrtf(s0) * -1.44269504f);
            float w1 = __builtin_amdgcn_exp2f(__builtin_amdgcn_sqrtf(s1) * -1.44269504f);
            unsigned u = pk_bf16(w0, w1);
            lp += bits_to_f(u << 16) + bits_to_f(u & 0xffff0000u);
            pk4[i >> 1] = u;
        }
        __syncthreads();  // prev iter's fragment reads done
        *(uint4*)(pbuf + r * PSTR + jq * 8) = make_uint4(pk4[0], pk4[1], pk4[2], pk4[3]);
        uint4* vd0 = (uint4*)(vbuf + t * PSTR);
        vd0[0] = va0; vd0[1] = va1; vd0[2] = va2; vd0[3] = va3;
        uint4* vd1 = (uint4*)(vbuf + (t + 256) * PSTR);
        vd1[0] = vb0; vd1[1] = vb1; vd1[2] = vb2; vd1[3] = vb3;
        __syncthreads();  // pbuf/vbuf visible

        const int col = lane & 15, quad = lane >> 4;
        bf16x8 a[4];
#pragma unroll
        for (int m = 0; m < 4; ++m)
            a[m] = *(const bf16x8*)(pbuf + (m * 16 + col) * PSTR + quad * 8);
#pragma unroll
        for (int n = 0; n < 8; ++n) {
            bf16x8 b = *(const bf16x8*)(vbuf + ((wv * 8 + n) * 16 + col) * PSTR + quad * 8);
#pragma unroll
            for (int m = 0; m < 4; ++m)
                acc[m][n] = __builtin_amdgcn_mfma_f32_16x16x32_bf16(a[m], b, acc[m][n], 0, 0, 0);
        }
    }

    red[t] = lp;
    __syncthreads();
    if (t < BM) lbuf[t] = red[t] + red[t + 64] + red[t + 128] + red[t + 192];
    __syncthreads();

    const int col = lane & 15, quad = lane >> 4;
#pragma unroll
    for (int m = 0; m < 4; ++m) {
        f32x4 l4 = *(const f32x4*)(lbuf + m * 16 + quad * 4);
        f32x4 inv4 = {1.0f / l4.x, 1.0f / l4.y, 1.0f / l4.z, 1.0f / l4.w};
        int qg = qb + m * 16 + quad * 4;
#pragma unroll
        for (int n = 0; n < 8; ++n) {
            int fg = (wv * 8 + n) * 16 + col;
            out[(size_t)(qg + 0) * F_DIM + fg] = acc[m][n].x * inv4.x;
            out[(size_t)(qg + 1) * F_DIM + fg] = acc[m][n].y * inv4.y;
            out[(size_t)(qg + 2) * F_DIM + fg] = acc[m][n].z * inv4.z;
            out[(size_t)(qg + 3) * F_DIM + fg] = acc[m][n].w * inv4.w;
        }
    }
}

// ---------------------------------------------------------------------------
// Workspace layout (bytes):
//   featT : [0,        8388608)   512x8192 bf16
//   memT  : [8388608, 16777216)   512x8192 bf16
//   npe4  : [16777216,16908288)   8192x4 fp32 (x,y,z,|npe|^2)
//   pn4   : [16908288,17039360)
//   en4   : [17039360,17170432)
//   pos4  : [17170432,17301504)
// ---------------------------------------------------------------------------
extern "C" void kernel_launch(void* const* d_in, const int* in_sizes, int n_in,
                              void* d_out, int out_size, void* d_ws, size_t ws_size,
                              hipStream_t stream) {
    const float* features  = (const float*)d_in[0];
    const float* positions = (const float*)d_in[1];
    const float* qpos      = (const float*)d_in[2];
    const float* pemb      = (const float*)d_in[3];
    float* out = (float*)d_out;
    char* ws = (char*)d_ws;

    unsigned short* featT = (unsigned short*)(ws);
    unsigned short* memT  = (unsigned short*)(ws + 8388608);
    float* npe4 = (float*)(ws + 16777216);
    float* pn4  = (float*)(ws + 16908288);
    float* en4  = (float*)(ws + 17039360);
    float* pos4 = (float*)(ws + 17170432);

    hipLaunchKernelGGL(prep_kernel, dim3(M_SZ / 256), dim3(256), 0, stream,
                       positions, pemb, pn4, en4, pos4);
    hipLaunchKernelGGL(transpose_kernel, dim3(M_SZ / 64, F_DIM / 64), dim3(256), 0, stream,
                       features, featT);
    hipLaunchKernelGGL(build_memory_kernel, dim3(M_SZ / 32, F_DIM / 256), dim3(256), 0, stream,
                       pn4, en4, pos4, featT, memT, npe4);
    hipLaunchKernelGGL(query_kernel, dim3(N_Q / 64), dim3(256), 0, stream,
                       qpos, npe4, memT, out);
}

// Round 4
// 815.343 us; speedup vs baseline: 1.2968x; 1.2968x over previous
//
#include <hip/hip_runtime.h>
#include <stdint.h>
#include <stddef.h>

#define M_SZ 8192
#define F_DIM 512
#define N_Q 32768

typedef __attribute__((ext_vector_type(4))) float f32x4;
typedef __attribute__((ext_vector_type(8))) __bf16 bf16x8;
typedef __attribute__((ext_vector_type(2))) __bf16 bf16x2;

__device__ __forceinline__ float bits_to_f(unsigned u) {
    union { unsigned u; float f; } v; v.u = u; return v.f;
}
// Pack two floats to bf16 pair (RNE, native cvt). Low 16 = a.
__device__ __forceinline__ unsigned pk_bf16(float a, float b) {
    union { bf16x2 v; unsigned u; } cv;
    cv.v.x = (__bf16)a; cv.v.y = (__bf16)b;
    return cv.u;
}
__device__ __forceinline__ unsigned short f2bf(float x) {
    union { bf16x2 v; unsigned u; } cv;
    cv.v.x = (__bf16)x; cv.v.y = (__bf16)0.0f;
    return (unsigned short)(cv.u & 0xffffu);
}
__device__ __forceinline__ bf16x8 as_bf16x8(uint4 u) {
    union { uint4 a; bf16x8 b; } cv; cv.a = u; return cv.b;
}

// ---------------------------------------------------------------------------
// Kernel 1: row-normalize positions & embeddings; pad to float4.
// ---------------------------------------------------------------------------
__global__ void prep_kernel(const float* __restrict__ pos,
                            const float* __restrict__ emb,
                            float* __restrict__ pn4,
                            float* __restrict__ en4,
                            float* __restrict__ pos4) {
    int i = blockIdx.x * 256 + threadIdx.x;
    if (i >= M_SZ) return;
    float x = pos[i * 3 + 0], y = pos[i * 3 + 1], z = pos[i * 3 + 2];
    float inv = 1.0f / __builtin_amdgcn_sqrtf(x * x + y * y + z * z);
    pn4[i * 4 + 0] = x * inv; pn4[i * 4 + 1] = y * inv;
    pn4[i * 4 + 2] = z * inv; pn4[i * 4 + 3] = 0.0f;
    pos4[i * 4 + 0] = x; pos4[i * 4 + 1] = y;
    pos4[i * 4 + 2] = z; pos4[i * 4 + 3] = 0.0f;
    float ex = emb[i * 3 + 0], ey = emb[i * 3 + 1], ez = emb[i * 3 + 2];
    float einv = 1.0f / __builtin_amdgcn_sqrtf(ex * ex + ey * ey + ez * ez);
    en4[i * 4 + 0] = ex * einv; en4[i * 4 + 1] = ey * einv;
    en4[i * 4 + 2] = ez * einv; en4[i * 4 + 3] = 0.0f;
}

// ---------------------------------------------------------------------------
// Kernel 2: features [8192,512] fp32 -> featT [512,8192] bf16.
// ---------------------------------------------------------------------------
__global__ void transpose_kernel(const float* __restrict__ feat,
                                 unsigned short* __restrict__ featT) {
    __shared__ float tile[64 * 65];
    const int jb = blockIdx.x * 64, fb = blockIdx.y * 64;
    const int t = threadIdx.x;
#pragma unroll
    for (int p = 0; p < 16; ++p) {
        int idx = p * 256 + t;
        int j = idx >> 6, f = idx & 63;
        tile[j * 65 + f] = feat[(size_t)(jb + j) * F_DIM + fb + f];
    }
    __syncthreads();
#pragma unroll
    for (int p = 0; p < 16; ++p) {
        int idx = p * 256 + t;
        int f = idx >> 6, j = idx & 63;
        featT[(size_t)(fb + f) * M_SZ + jb + j] = f2bf(tile[j * 65 + f]);
    }
}

// ---------------------------------------------------------------------------
// Kernel 3: fused softmax(pn@en^T) @ [features | positions] -> memT, npe4.
// BM=32, BN=512 (full F, P once), BK=32, 512 threads, 256 blocks (1/CU).
// B-fragments loaded direct global->reg (prefetched one iter ahead);
// P double-buffered in LDS -> ONE barrier per K-iter.
// ---------------------------------------------------------------------------
__launch_bounds__(512, 2)
__global__ void build_memory_kernel(const float* __restrict__ pn4,
                                    const float* __restrict__ en4,
                                    const float* __restrict__ pos4,
                                    const unsigned short* __restrict__ featT,
                                    unsigned short* __restrict__ memT,
                                    float* __restrict__ npe4) {
    constexpr int BM = 32, BK = 32, PSTR = BK + 8;  // 40 shorts = 80 B row
    __shared__ unsigned short pbuf[2][BM * PSTR];
    __shared__ f32x4 red4[512];
    __shared__ float lbuf[BM];

    const int t = threadIdx.x;
    const int lane = t & 63, wv = t >> 6;
    const int col = lane & 15, quad = lane >> 4;
    const int mb = blockIdx.x * BM;
    const int r = t & 31, jq = t >> 5;  // P-row, j-group (2 each)

    const f32x4 pnr = ((const f32x4*)pn4)[mb + r];
    const f32x4* en = (const f32x4*)en4;
    const f32x4* ps = (const f32x4*)pos4;

    // B-fragment pointers: rows wv*64 + n*16 + col of featT, k = quad*8
    const unsigned short* bp[4];
#pragma unroll
    for (int n = 0; n < 4; ++n)
        bp[n] = featT + (size_t)(wv * 64 + n * 16 + col) * M_SZ + quad * 8;

    f32x4 acc[2][4];
    const f32x4 zero4 = {0.f, 0.f, 0.f, 0.f};
#pragma unroll
    for (int m = 0; m < 2; ++m)
#pragma unroll
        for (int n = 0; n < 4; ++n) acc[m][n] = zero4;
    float nx = 0.f, ny = 0.f, nz = 0.f, lp = 0.f;

    uint4 vbA[4], vbB[4];
#pragma unroll
    for (int n = 0; n < 4; ++n) vbA[n] = *(const uint4*)(bp[n]);

#define B_GEN_P(JB, SIDE)                                                    \
    {                                                                        \
        int j = (JB) + jq * 2;                                               \
        f32x4 e0 = en[j], e1 = en[j + 1];                                    \
        f32x4 p0 = ps[j], p1 = ps[j + 1];                                    \
        float s0 = fmaf(pnr.x, e0.x, fmaf(pnr.y, e0.y, pnr.z * e0.z));       \
        float s1 = fmaf(pnr.x, e1.x, fmaf(pnr.y, e1.y, pnr.z * e1.z));       \
        float w0 = __builtin_amdgcn_exp2f(s0 * 1.44269504f);                 \
        float w1 = __builtin_amdgcn_exp2f(s1 * 1.44269504f);                 \
        unsigned u = pk_bf16(w0, w1);                                        \
        float w0r = bits_to_f(u << 16), w1r = bits_to_f(u & 0xffff0000u);    \
        lp += w0r + w1r;                                                     \
        nx = fmaf(w0r, p0.x, fmaf(w1r, p1.x, nx));                           \
        ny = fmaf(w0r, p0.y, fmaf(w1r, p1.y, ny));                           \
        nz = fmaf(w0r, p0.z, fmaf(w1r, p1.z, nz));                           \
        *(unsigned*)(&pbuf[SIDE][r * PSTR + jq * 2]) = u;                    \
    }

#define B_MFMA(VB, SIDE)                                                     \
    {                                                                        \
        _Pragma("unroll") for (int m = 0; m < 2; ++m) {                      \
            bf16x8 a = *(const bf16x8*)(&pbuf[SIDE][(m * 16 + col) * PSTR + quad * 8]); \
            _Pragma("unroll") for (int n = 0; n < 4; ++n)                    \
                acc[m][n] = __builtin_amdgcn_mfma_f32_16x16x32_bf16(         \
                    a, as_bf16x8(VB[n]), acc[m][n], 0, 0, 0);                \
        }                                                                    \
    }

#define B_BODY(CUR, NXT, SIDE, JNXT)                                         \
    {                                                                        \
        _Pragma("unroll") for (int n = 0; n < 4; ++n) {                      \
            NXT[n] = *(const uint4*)(bp[n] + BK);                            \
            bp[n] += BK;                                                     \
        }                                                                    \
        B_GEN_P(JNXT, SIDE ^ 1)                                              \
        B_MFMA(CUR, SIDE)                                                    \
        __syncthreads();                                                     \
    }

    // prologue: P(0)
    B_GEN_P(0, 0)
    __syncthreads();

    int jn = BK;
    for (int kt = 0; kt < 254; kt += 2) {
        B_BODY(vbA, vbB, 0, jn) jn += BK;
        B_BODY(vbB, vbA, 1, jn) jn += BK;
    }
    B_BODY(vbA, vbB, 0, jn)   // kt = 254: prefetch V(255), P(255)->pbuf[1]
    B_MFMA(vbB, 1)            // kt = 255
#undef B_BODY
#undef B_MFMA
#undef B_GEN_P

    f32x4 mine = {nx, ny, nz, lp};
    red4[t] = mine;
    __syncthreads();
    if (t < BM) {
        f32x4 s = red4[t];
#pragma unroll
        for (int g = 1; g < 16; ++g) {
            f32x4 o = red4[t + 32 * g];
            s.x += o.x; s.y += o.y; s.z += o.z; s.w += o.w;
        }
        lbuf[t] = s.w;
        float inv = 1.0f / s.w;
        float X = s.x * inv, Y = s.y * inv, Z = s.z * inv;
        f32x4 o = {X, Y, Z, X * X + Y * Y + Z * Z};
        ((f32x4*)npe4)[mb + t] = o;
    }
    __syncthreads();

    // memT[f][m] = acc/l (C layout: col=lane&15, row=quad*4+reg)
#pragma unroll
    for (int m = 0; m < 2; ++m) {
        f32x4 l4 = *(const f32x4*)(lbuf + m * 16 + quad * 4);
        f32x4 inv4 = {1.0f / l4.x, 1.0f / l4.y, 1.0f / l4.z, 1.0f / l4.w};
        int mg = mb + m * 16 + quad * 4;
#pragma unroll
        for (int n = 0; n < 4; ++n) {
            int fg = wv * 64 + n * 16 + col;
            uint2 o;
            o.x = pk_bf16(acc[m][n].x * inv4.x, acc[m][n].y * inv4.y);
            o.y = pk_bf16(acc[m][n].z * inv4.z, acc[m][n].w * inv4.w);
            *(uint2*)(memT + (size_t)fg * M_SZ + mg) = o;
        }
    }
}

// ---------------------------------------------------------------------------
// Kernel 4: fused softmax(-cdist(q, npe)) @ memory.
// BM=128, BN=512, BK=32, 512 threads, 256 blocks (1/CU, acc=128/thread).
// Direct-to-reg B with one-iter prefetch; double-buffered P; 1 barrier/iter.
// ---------------------------------------------------------------------------
__launch_bounds__(512, 2)
__global__ void query_kernel(const float* __restrict__ qpos,
                             const float* __restrict__ npe4,
                             const unsigned short* __restrict__ memT,
                             float* __restrict__ out) {
    constexpr int BM = 128, BK = 32, PSTR = BK + 8;  // 40
    __shared__ unsigned short pbuf[2][BM * PSTR];    // 2 x 10240 B
    __shared__ float redl[512];
    __shared__ float lbuf[BM];

    const int t = threadIdx.x;
    const int lane = t & 63, wv = t >> 6;
    const int col = lane & 15, quad = lane >> 4;
    const int qb = blockIdx.x * BM;
    const int r = t & 127, jq = t >> 7;  // P-row, j-group (8 each)

    const float qx = qpos[(size_t)(qb + r) * 3 + 0];
    const float qy = qpos[(size_t)(qb + r) * 3 + 1];
    const float qz = qpos[(size_t)(qb + r) * 3 + 2];
    const float q2 = qx * qx + qy * qy + qz * qz;
    const float m2x = -2.0f * qx, m2y = -2.0f * qy, m2z = -2.0f * qz;

    const f32x4* nsrc = (const f32x4*)npe4;

    const unsigned short* bp[4];
#pragma unroll
    for (int n = 0; n < 4; ++n)
        bp[n] = memT + (size_t)(wv * 64 + n * 16 + col) * M_SZ + quad * 8;

    f32x4 acc[8][4];
    const f32x4 zero4 = {0.f, 0.f, 0.f, 0.f};
#pragma unroll
    for (int m = 0; m < 8; ++m)
#pragma unroll
        for (int n = 0; n < 4; ++n) acc[m][n] = zero4;
    float lp = 0.f;

    uint4 vbA[4], vbB[4];
#pragma unroll
    for (int n = 0; n < 4; ++n) vbA[n] = *(const uint4*)(bp[n]);

#define Q_GEN_P(JB, SIDE)                                                    \
    {                                                                        \
        unsigned pk4[4];                                                     \
        _Pragma("unroll") for (int i = 0; i < 8; i += 2) {                   \
            int j = (JB) + jq * 8 + i;                                       \
            f32x4 n0 = nsrc[j], n1 = nsrc[j + 1];                            \
            float s0 = fmaf(m2x, n0.x, fmaf(m2y, n0.y, fmaf(m2z, n0.z, q2 + n0.w))); \
            float s1 = fmaf(m2x, n1.x, fmaf(m2y, n1.y, fmaf(m2z, n1.z, q2 + n1.w))); \
            s0 = fmaxf(s0, 1e-12f); s1 = fmaxf(s1, 1e-12f);                  \
            float w0 = __builtin_amdgcn_exp2f(__builtin_amdgcn_sqrtf(s0) * -1.44269504f); \
            float w1 = __builtin_amdgcn_exp2f(__builtin_amdgcn_sqrtf(s1) * -1.44269504f); \
            unsigned u = pk_bf16(w0, w1);                                    \
            lp += bits_to_f(u << 16) + bits_to_f(u & 0xffff0000u);           \
            pk4[i >> 1] = u;                                                 \
        }                                                                    \
        *(uint4*)(&pbuf[SIDE][r * PSTR + jq * 8]) =                          \
            make_uint4(pk4[0], pk4[1], pk4[2], pk4[3]);                      \
    }

#define Q_MFMA(VB, SIDE)                                                     \
    {                                                                        \
        _Pragma("unroll") for (int m = 0; m < 8; ++m) {                      \
            bf16x8 a = *(const bf16x8*)(&pbuf[SIDE][(m * 16 + col) * PSTR + quad * 8]); \
            _Pragma("unroll") for (int n = 0; n < 4; ++n)                    \
                acc[m][n] = __builtin_amdgcn_mfma_f32_16x16x32_bf16(         \
                    a, as_bf16x8(VB[n]), acc[m][n], 0, 0, 0);                \
        }                                                                    \
    }

#define Q_BODY(CUR, NXT, SIDE, JNXT)                                         \
    {                                                                        \
        _Pragma("unroll") for (int n = 0; n < 4; ++n) {                      \
            NXT[n] = *(const uint4*)(bp[n] + BK);                            \
            bp[n] += BK;                                                     \
        }                                                                    \
        Q_GEN_P(JNXT, SIDE ^ 1)                                              \
        Q_MFMA(CUR, SIDE)                                                    \
        __syncthreads();                                                     \
    }

    Q_GEN_P(0, 0)
    __syncthreads();

    int jn = BK;
    for (int kt = 0; kt < 254; kt += 2) {
        Q_BODY(vbA, vbB, 0, jn) jn += BK;
        Q_BODY(vbB, vbA, 1, jn) jn += BK;
    }
    Q_BODY(vbA, vbB, 0, jn)   // kt = 254
    Q_MFMA(vbB, 1)            // kt = 255
#undef Q_BODY
#undef Q_MFMA
#undef Q_GEN_P

    redl[t] = lp;
    __syncthreads();
    if (t < BM) lbuf[t] = redl[t] + redl[t + 128] + redl[t + 256] + redl[t + 384];
    __syncthreads();

#pragma unroll
    for (int m = 0; m < 8; ++m) {
        f32x4 l4 = *(const f32x4*)(lbuf + m * 16 + quad * 4);
        f32x4 inv4 = {1.0f / l4.x, 1.0f / l4.y, 1.0f / l4.z, 1.0f / l4.w};
        int qg = qb + m * 16 + quad * 4;
#pragma unroll
        for (int n = 0; n < 4; ++n) {
            int fg = wv * 64 + n * 16 + col;
            out[(size_t)(qg + 0) * F_DIM + fg] = acc[m][n].x * inv4.x;
            out[(size_t)(qg + 1) * F_DIM + fg] = acc[m][n].y * inv4.y;
            out[(size_t)(qg + 2) * F_DIM + fg] = acc[m][n].z * inv4.z;
            out[(size_t)(qg + 3) * F_DIM + fg] = acc[m][n].w * inv4.w;
        }
    }
}

// ---------------------------------------------------------------------------
// Workspace layout (bytes):
//   featT : [0,        8388608)   512x8192 bf16
//   memT  : [8388608, 16777216)   512x8192 bf16
//   npe4  : [16777216,16908288)   8192x4 fp32 (x,y,z,|npe|^2)
//   pn4   : [16908288,17039360)
//   en4   : [17039360,17170432)
//   pos4  : [17170432,17301504)
// ---------------------------------------------------------------------------
extern "C" void kernel_launch(void* const* d_in, const int* in_sizes, int n_in,
                              void* d_out, int out_size, void* d_ws, size_t ws_size,
                              hipStream_t stream) {
    const float* features  = (const float*)d_in[0];
    const float* positions = (const float*)d_in[1];
    const float* qpos      = (const float*)d_in[2];
    const float* pemb      = (const float*)d_in[3];
    float* out = (float*)d_out;
    char* ws = (char*)d_ws;

    unsigned short* featT = (unsigned short*)(ws);
    unsigned short* memT  = (unsigned short*)(ws + 8388608);
    float* npe4 = (float*)(ws + 16777216);
    float* pn4  = (float*)(ws + 16908288);
    float* en4  = (float*)(ws + 17039360);
    float* pos4 = (float*)(ws + 17170432);

    hipLaunchKernelGGL(prep_kernel, dim3(M_SZ / 256), dim3(256), 0, stream,
                       positions, pemb, pn4, en4, pos4);
    hipLaunchKernelGGL(transpose_kernel, dim3(M_SZ / 64, F_DIM / 64), dim3(256), 0, stream,
                       features, featT);
    hipLaunchKernelGGL(build_memory_kernel, dim3(M_SZ / 32), dim3(512), 0, stream,
                       pn4, en4, pos4, featT, memT, npe4);
    hipLaunchKernelGGL(query_kernel, dim3(N_Q / 128), dim3(512), 0, stream,
                       qpos, npe4, memT, out);
}